// Round 8
// baseline (302.649 us; speedup 1.0000x reference)
//
#include <hip/hip_runtime.h>

#define NNODES 100000
#define NEDGES 1000000
#define DD 64
#define DD2 128
#define NT 64                 // nodes per tile in node passes
#define NTILES ((NNODES + NT - 1) / NT)
#define SCAN_B ((NNODES + 256) / 256 + 1)   // 392 blocks covers i in [0, NNODES]

__device__ __forceinline__ unsigned bf16pack(float a, float b) {
    unsigned ua = __float_as_uint(a);
    unsigned ub = __float_as_uint(b);
    ua = (ua + 0x7fffu + ((ua >> 16) & 1u)) >> 16;
    ub = (ub + 0x7fffu + ((ub >> 16) & 1u)) >> 16;
    return ua | (ub << 16);
}
__device__ __forceinline__ float bf16lo(unsigned u) { return __uint_as_float(u << 16); }
__device__ __forceinline__ float bf16hi(unsigned u) { return __uint_as_float(u & 0xffff0000u); }

// ---------------- histogram: cnt[dst]++ (4 edges/thread)
__global__ void hist_kernel(const int* __restrict__ ei, int* __restrict__ cnt) {
    int e4 = blockIdx.x * 256 + threadIdx.x;
    if (e4 * 4 >= NEDGES) return;
    int4 t = *(const int4*)&ei[NEDGES + e4 * 4];
    atomicAdd(&cnt[t.x], 1);
    atomicAdd(&cnt[t.y], 1);
    atomicAdd(&cnt[t.z], 1);
    atomicAdd(&cnt[t.w], 1);
}

// ---------------- scan pass 1: block-local exclusive scan of cnt -> rowptr (local),
// block total -> bsum[b]
__global__ void scan1_kernel(const int* __restrict__ cnt,
                             int* __restrict__ rowptr,
                             int* __restrict__ bsum) {
    __shared__ int sc[256];
    const int t = threadIdx.x;
    const int i = blockIdx.x * 256 + t;
    int v = (i < NNODES) ? cnt[i] : 0;
    sc[t] = v;
    __syncthreads();
#pragma unroll
    for (int off = 1; off < 256; off <<= 1) {
        int tmp = (t >= off) ? sc[t - off] : 0;
        __syncthreads();
        sc[t] += tmp;
        __syncthreads();
    }
    if (i <= NNODES) rowptr[i] = sc[t] - v;   // local exclusive
    if (t == 255) bsum[blockIdx.x] = sc[255];
}

// ---------------- scan pass 2: serial exclusive scan of block sums
__global__ void scan2_kernel(const int* __restrict__ bsum, int* __restrict__ boff) {
    if (threadIdx.x == 0) {
        int run = 0;
        for (int b = 0; b < SCAN_B; ++b) { boff[b] = run; run += bsum[b]; }
    }
}

// ---------------- scan pass 3: add block offsets; init working counters
__global__ void scan3_kernel(int* __restrict__ rowptr,
                             const int* __restrict__ boff,
                             int* __restrict__ wctr) {
    const int i = blockIdx.x * 256 + threadIdx.x;
    if (i <= NNODES) {
        int r = rowptr[i] + boff[blockIdx.x];
        rowptr[i] = r;
        if (i < NNODES) wctr[i] = r;
    }
}

// ---------------- scatter into CSR adjacency (4 MB -> L2-resident stores)
__global__ void scatter_kernel(const int* __restrict__ ei,
                               int* __restrict__ wctr,
                               int* __restrict__ adj) {
    int e4 = blockIdx.x * 256 + threadIdx.x;
    if (e4 * 4 >= NEDGES) return;
    int4 s = *(const int4*)&ei[e4 * 4];
    int4 t = *(const int4*)&ei[NEDGES + e4 * 4];
    int p;
    p = atomicAdd(&wctr[t.x], 1); adj[p] = s.x;
    p = atomicAdd(&wctr[t.y], 1); adj[p] = s.y;
    p = atomicAdd(&wctr[t.z], 1); adj[p] = s.z;
    p = atomicAdd(&wctr[t.w], 1); adj[p] = s.w;
}

// ---------------- softmax aggregation over CSR.
// one wave per node; 4 groups of 16 lanes; 16-deep edge pipeline (4 gathers in flight).
__global__ void __launch_bounds__(256) agg_kernel(const float* __restrict__ x,
                                                  const int* __restrict__ rowptr,
                                                  const int* __restrict__ adj,
                                                  float* __restrict__ outbuf) {
    const int lane = threadIdx.x & 63;
    const int grp = lane >> 4;      // 0..3: edge slot within quad
    const int sub = lane & 15;      // dims [4*sub, 4*sub+4)
    const int wid = (blockIdx.x * blockDim.x + threadIdx.x) >> 6;
    const int nwaves = (gridDim.x * blockDim.x) >> 6;
    for (int n = wid; n < NNODES; n += nwaves) {
        const int start = rowptr[n];
        const int deg = rowptr[n + 1] - start;
        float4 num = {0.f, 0.f, 0.f, 0.f}, den = {0.f, 0.f, 0.f, 0.f};
        for (int base = 0; base < deg; base += 16) {
            int eA = base + grp, eB = eA + 4, eC = eA + 8, eD = eA + 12;
            int sA = (eA < deg) ? adj[start + eA] : 0;
            int sB = (eB < deg) ? adj[start + eB] : 0;
            int sC = (eC < deg) ? adj[start + eC] : 0;
            int sD = (eD < deg) ? adj[start + eD] : 0;
            const float4 vA = *(const float4*)&x[(size_t)sA * DD + sub * 4];
            const float4 vB = *(const float4*)&x[(size_t)sB * DD + sub * 4];
            const float4 vC = *(const float4*)&x[(size_t)sC * DD + sub * 4];
            const float4 vD = *(const float4*)&x[(size_t)sD * DD + sub * 4];
            float valA = (eA < deg) ? 1.f : 0.f;
            float valB = (eB < deg) ? 1.f : 0.f;
            float valC = (eC < deg) ? 1.f : 0.f;
            float valD = (eD < deg) ? 1.f : 0.f;
#define ACC(v, val)                                                        \
            {                                                              \
                float m0 = fmaxf(v.x, 0.f) + 1e-7f; float x0 = __expf(m0) * val; \
                float m1 = fmaxf(v.y, 0.f) + 1e-7f; float x1 = __expf(m1) * val; \
                float m2 = fmaxf(v.z, 0.f) + 1e-7f; float x2 = __expf(m2) * val; \
                float m3 = fmaxf(v.w, 0.f) + 1e-7f; float x3 = __expf(m3) * val; \
                den.x += x0; num.x = fmaf(m0, x0, num.x);                  \
                den.y += x1; num.y = fmaf(m1, x1, num.y);                  \
                den.z += x2; num.z = fmaf(m2, x2, num.z);                  \
                den.w += x3; num.w = fmaf(m3, x3, num.w);                  \
            }
            ACC(vA, valA) ACC(vB, valB) ACC(vC, valC) ACC(vD, valD)
#undef ACC
        }
#pragma unroll
        for (int off = 16; off <= 32; off <<= 1) {
            num.x += __shfl_xor(num.x, off, 64);
            num.y += __shfl_xor(num.y, off, 64);
            num.z += __shfl_xor(num.z, off, 64);
            num.w += __shfl_xor(num.w, off, 64);
            den.x += __shfl_xor(den.x, off, 64);
            den.y += __shfl_xor(den.y, off, 64);
            den.z += __shfl_xor(den.z, off, 64);
            den.w += __shfl_xor(den.w, off, 64);
        }
        if (grp == 0) {
            const float4 xr = *(const float4*)&x[(size_t)n * DD + sub * 4];
            float4 o;
            o.x = num.x / (den.x + 1e-16f) + xr.x;
            o.y = num.y / (den.y + 1e-16f) + xr.y;
            o.z = num.z / (den.z + 1e-16f) + xr.z;
            o.w = num.w / (den.w + 1e-16f) + xr.w;
            *(float4*)&outbuf[(size_t)n * DD + sub * 4] = o;
        }
    }
}

// ---------------- node pass 1: h = out@W1 + b1 via transposed LDS tile;
// store h bf16-packed; BN stats via LDS transpose. sOutT/sHT aliased.
__global__ void __launch_bounds__(256) node1_kernel(
        const float* __restrict__ outbuf,
        const float* __restrict__ W1,
        const float* __restrict__ b1,
        float* __restrict__ sums,
        float* __restrict__ sumsq,
        unsigned* __restrict__ hbuf) {
    __shared__ float smem[DD2 * (NT + 1)];
    __shared__ float sRed[2][DD2];
    float (*sOutT)[NT + 1] = (float (*)[NT + 1])smem;
    float (*sHT)[NT + 1] = (float (*)[NT + 1])smem;
    const int tid = threadIdx.x;
    const int n0 = blockIdx.x * NT;

#pragma unroll
    for (int j = 0; j < 16; ++j) {
        int f = j * 256 + tid;
        int n = f >> 6, d = f & 63;
        float o = (n0 + n < NNODES) ? outbuf[(size_t)n0 * DD + f] : 0.f;
        sOutT[d][n] = o;
    }
    __syncthreads();

    const int node = tid & 63;
    const int cg = __builtin_amdgcn_readfirstlane(tid >> 6);
    const int nn = n0 + node;
    const float* __restrict__ W1c = W1 + cg * 32;
    const float* __restrict__ b1c = b1 + cg * 32;
    float acc[32];
#pragma unroll
    for (int j = 0; j < 32; ++j) acc[j] = b1c[j];
#pragma unroll 16
    for (int k = 0; k < DD; ++k) {
        float a = sOutT[k][node];
#pragma unroll
        for (int j = 0; j < 32; ++j) acc[j] = fmaf(a, W1c[k * DD2 + j], acc[j]);
    }
    if (nn < NNODES) {
        unsigned hp[16];
#pragma unroll
        for (int j = 0; j < 16; ++j) hp[j] = bf16pack(acc[2 * j], acc[2 * j + 1]);
        uint4* dst = (uint4*)(hbuf + (size_t)nn * (DD2 / 2) + cg * 16);
#pragma unroll
        for (int i = 0; i < 4; ++i) dst[i] = ((uint4*)hp)[i];
    }
    __syncthreads();

#pragma unroll
    for (int j = 0; j < 32; ++j) sHT[cg * 32 + j][node] = acc[j];
    __syncthreads();
    const int c = tid & 127, half = tid >> 7;
    float s = 0.f, q = 0.f;
#pragma unroll
    for (int i = 0; i < 32; ++i) {
        if (n0 + half * 32 + i < NNODES) {
            float v = sHT[c][half * 32 + i];
            s += v;
            q = fmaf(v, v, q);
        }
    }
    if (half) { sRed[0][c] = s; sRed[1][c] = q; }
    __syncthreads();
    if (!half) {
        atomicAdd(&sums[c], s + sRed[0][c]);
        atomicAdd(&sumsq[c], q + sRed[1][c]);
    }
}

// ---------------- BN finalize
__global__ void bn_finalize(const float* __restrict__ sums,
                            const float* __restrict__ sumsq,
                            const float* __restrict__ gamma,
                            const float* __restrict__ beta,
                            float* __restrict__ A, float* __restrict__ B) {
    int c = threadIdx.x;
    float inv_n = 1.0f / (float)NNODES;
    float mu = sums[c] * inv_n;
    float var = sumsq[c] * inv_n - mu * mu;
    float a = rsqrtf(var + 1e-5f) * gamma[c];
    A[c] = a;
    B[c] = beta[c] - mu * a;
}

// ---------------- node pass 2: h -> BN -> relu -> y=h@W2+b2 -> LN -> relu
__global__ void __launch_bounds__(256) node2_kernel(
        const unsigned* __restrict__ hbuf,
        const float* __restrict__ A,
        const float* __restrict__ B,
        const float* __restrict__ W2,
        const float* __restrict__ b2,
        const float* __restrict__ lng,
        const float* __restrict__ lnb,
        float* __restrict__ out) {
    __shared__ float sLN[2][4][NT];
    const int tid = threadIdx.x;
    const int n0 = blockIdx.x * NT;
    const int node = tid & 63;
    const int cg = __builtin_amdgcn_readfirstlane(tid >> 6);
    const int nn = n0 + node;
    const int nc = min(nn, NNODES - 1);
    const float* __restrict__ W2c = W2 + cg * 16;

    float y[16];
#pragma unroll
    for (int j = 0; j < 16; ++j) y[j] = b2[cg * 16 + j];

#pragma unroll
    for (int c2 = 0; c2 < 2; ++c2) {
        float hrow[64];
        const uint4* hp = (const uint4*)(hbuf + (size_t)nc * (DD2 / 2) + c2 * 32);
#pragma unroll
        for (int i = 0; i < 8; ++i) {
            uint4 u = hp[i];
            hrow[i * 8 + 0] = bf16lo(u.x); hrow[i * 8 + 1] = bf16hi(u.x);
            hrow[i * 8 + 2] = bf16lo(u.y); hrow[i * 8 + 3] = bf16hi(u.y);
            hrow[i * 8 + 4] = bf16lo(u.z); hrow[i * 8 + 5] = bf16hi(u.z);
            hrow[i * 8 + 6] = bf16lo(u.w); hrow[i * 8 + 7] = bf16hi(u.w);
        }
#pragma unroll
        for (int j = 0; j < 64; ++j) {
            int c = c2 * 64 + j;
            hrow[j] = fmaxf(fmaf(hrow[j], A[c], B[c]), 0.f);
        }
#pragma unroll
        for (int k = 0; k < 64; ++k) {
            float hv = hrow[k];
#pragma unroll
            for (int j = 0; j < 16; ++j)
                y[j] = fmaf(hv, W2c[(c2 * 64 + k) * DD + j], y[j]);
        }
    }
    float ps = 0.f, pq = 0.f;
#pragma unroll
    for (int j = 0; j < 16; ++j) { ps += y[j]; pq = fmaf(y[j], y[j], pq); }
    sLN[0][cg][node] = ps;
    sLN[1][cg][node] = pq;
    __syncthreads();
    float s = sLN[0][0][node] + sLN[0][1][node] + sLN[0][2][node] + sLN[0][3][node];
    float q = sLN[1][0][node] + sLN[1][1][node] + sLN[1][2][node] + sLN[1][3][node];
    float mu = s * (1.0f / DD);
    float var = q * (1.0f / DD) - mu * mu;
    float rs = rsqrtf(var + 1e-5f);
    if (nn < NNODES) {
        float o[16];
#pragma unroll
        for (int j = 0; j < 16; ++j)
            o[j] = fmaxf(fmaf((y[j] - mu) * rs, lng[cg * 16 + j], lnb[cg * 16 + j]), 0.f);
        float4* op = (float4*)(out + (size_t)nn * DD + cg * 16);
#pragma unroll
        for (int i = 0; i < 4; ++i) op[i] = ((float4*)o)[i];
    }
}

extern "C" void kernel_launch(void* const* d_in, const int* in_sizes, int n_in,
                              void* d_out, int out_size, void* d_ws, size_t ws_size,
                              hipStream_t stream) {
    const float* x    = (const float*)d_in[0];
    const int*   ei   = (const int*)d_in[1];
    const float* W1   = (const float*)d_in[2];
    const float* b1   = (const float*)d_in[3];
    const float* bn_g = (const float*)d_in[4];
    const float* bn_b = (const float*)d_in[5];
    const float* W2   = (const float*)d_in[6];
    const float* b2   = (const float*)d_in[7];
    const float* ln_g = (const float*)d_in[8];
    const float* ln_b = (const float*)d_in[9];
    float* out = (float*)d_out;

    // ws: cnt[N] | sums[128] | sumsq[128] | A[128] | B[128] | bsum[512] | boff[512]
    //   | rowptr[N+1] | wctr[N] | adj[E] | hbuf[N*64] (uint)
    int*      cnt    = (int*)d_ws;
    float*    sums   = (float*)(cnt + NNODES);
    float*    sumsq  = sums + DD2;
    float*    A      = sumsq + DD2;
    float*    B      = A + DD2;
    int*      bsum   = (int*)(B + DD2);
    int*      boff   = bsum + 512;
    int*      rowptr = boff + 512;
    int*      wctr   = rowptr + NNODES + 1;
    int*      adj    = wctr + NNODES;
    unsigned* hbuf   = (unsigned*)(adj + NEDGES);

    // zero cnt + sums + sumsq (contiguous at start of ws)
    hipMemsetAsync(d_ws, 0, (size_t)(NNODES + 2 * DD2) * sizeof(int), stream);

    hist_kernel<<<(NEDGES / 4 + 255) / 256, 256, 0, stream>>>(ei, cnt);
    scan1_kernel<<<SCAN_B, 256, 0, stream>>>(cnt, rowptr, bsum);
    scan2_kernel<<<1, 64, 0, stream>>>(bsum, boff);
    scan3_kernel<<<SCAN_B, 256, 0, stream>>>(rowptr, boff, wctr);
    scatter_kernel<<<(NEDGES / 4 + 255) / 256, 256, 0, stream>>>(ei, wctr, adj);
    agg_kernel<<<2048, 256, 0, stream>>>(x, rowptr, adj, out);
    node1_kernel<<<NTILES, 256, 0, stream>>>(out, W1, b1, sums, sumsq, hbuf);
    bn_finalize<<<1, DD2, 0, stream>>>(sums, sumsq, bn_g, bn_b, A, B);
    node2_kernel<<<NTILES, 256, 0, stream>>>(hbuf, A, B, W2, b2, ln_g, ln_b, out);
}

// Round 9
// 286.309 us; speedup vs baseline: 1.0571x; 1.0571x over previous
//
#include <hip/hip_runtime.h>

#define NNODES 100000
#define NEDGES 1000000
#define DD 64
#define DD2 128
#define NT 64                 // nodes per tile in node passes
#define NTILES ((NNODES + NT - 1) / NT)
#define SCAN_B ((NNODES + 256) / 256 + 1)   // 392 blocks covers i in [0, NNODES]
#define RS_G 8                              // XCD-local groups
#define RS_RANGE ((NNODES + RS_G - 1) / RS_G)   // 12500 nodes per group
#define RS_NB 256                           // blocks per group

__device__ __forceinline__ unsigned bf16pack(float a, float b) {
    unsigned ua = __float_as_uint(a);
    unsigned ub = __float_as_uint(b);
    ua = (ua + 0x7fffu + ((ua >> 16) & 1u)) >> 16;
    ub = (ub + 0x7fffu + ((ub >> 16) & 1u)) >> 16;
    return ua | (ub << 16);
}
__device__ __forceinline__ float bf16lo(unsigned u) { return __uint_as_float(u << 16); }
__device__ __forceinline__ float bf16hi(unsigned u) { return __uint_as_float(u & 0xffff0000u); }

// ---------------- histogram: XCD-local node ranges; group sweeps dst stream.
__global__ void hist_kernel(const int* __restrict__ ei, int* __restrict__ cnt) {
    const int group = blockIdx.x & (RS_G - 1);   // ~XCD id (dispatch round-robin)
    const int blk = blockIdx.x >> 3;
    const int lo = group * RS_RANGE;
    const int hi = min(lo + RS_RANGE, NNODES);
    for (int e4 = blk * 256 + threadIdx.x; e4 < NEDGES / 4; e4 += RS_NB * 256) {
        int4 t = *(const int4*)&ei[NEDGES + e4 * 4];
        if (t.x >= lo && t.x < hi) atomicAdd(&cnt[t.x], 1);
        if (t.y >= lo && t.y < hi) atomicAdd(&cnt[t.y], 1);
        if (t.z >= lo && t.z < hi) atomicAdd(&cnt[t.z], 1);
        if (t.w >= lo && t.w < hi) atomicAdd(&cnt[t.w], 1);
    }
}

// ---------------- scan pass 1: block-local exclusive scan of cnt -> rowptr (local),
// block total -> bsum[b]
__global__ void scan1_kernel(const int* __restrict__ cnt,
                             int* __restrict__ rowptr,
                             int* __restrict__ bsum) {
    __shared__ int sc[256];
    const int t = threadIdx.x;
    const int i = blockIdx.x * 256 + t;
    int v = (i < NNODES) ? cnt[i] : 0;
    sc[t] = v;
    __syncthreads();
#pragma unroll
    for (int off = 1; off < 256; off <<= 1) {
        int tmp = (t >= off) ? sc[t - off] : 0;
        __syncthreads();
        sc[t] += tmp;
        __syncthreads();
    }
    if (i <= NNODES) rowptr[i] = sc[t] - v;   // local exclusive
    if (t == 255) bsum[blockIdx.x] = sc[255];
}

// ---------------- scan pass 2: parallel scan of block sums (one 512-thread block)
__global__ void scan2_kernel(const int* __restrict__ bsum, int* __restrict__ boff) {
    __shared__ int sc[512];
    const int t = threadIdx.x;
    int v = (t < SCAN_B) ? bsum[t] : 0;
    sc[t] = v;
    __syncthreads();
#pragma unroll
    for (int off = 1; off < 512; off <<= 1) {
        int tmp = (t >= off) ? sc[t - off] : 0;
        __syncthreads();
        sc[t] += tmp;
        __syncthreads();
    }
    if (t < SCAN_B) boff[t] = sc[t] - v;      // exclusive
}

// ---------------- scan pass 3: add block offsets; init working counters
__global__ void scan3_kernel(int* __restrict__ rowptr,
                             const int* __restrict__ boff,
                             int* __restrict__ wctr) {
    const int i = blockIdx.x * 256 + threadIdx.x;
    if (i <= NNODES) {
        int r = rowptr[i] + boff[blockIdx.x];
        rowptr[i] = r;
        if (i < NNODES) wctr[i] = r;
    }
}

// ---------------- scatter into CSR adjacency, XCD-local ranges.
__global__ void scatter_kernel(const int* __restrict__ ei,
                               int* __restrict__ wctr,
                               int* __restrict__ adj) {
    const int group = blockIdx.x & (RS_G - 1);
    const int blk = blockIdx.x >> 3;
    const int lo = group * RS_RANGE;
    const int hi = min(lo + RS_RANGE, NNODES);
    for (int e4 = blk * 256 + threadIdx.x; e4 < NEDGES / 4; e4 += RS_NB * 256) {
        int4 t = *(const int4*)&ei[NEDGES + e4 * 4];
        bool ix = (t.x >= lo && t.x < hi);
        bool iy = (t.y >= lo && t.y < hi);
        bool iz = (t.z >= lo && t.z < hi);
        bool iw = (t.w >= lo && t.w < hi);
        if (ix | iy | iz | iw) {
            int4 s = *(const int4*)&ei[e4 * 4];
            int p;
            if (ix) { p = atomicAdd(&wctr[t.x], 1); adj[p] = s.x; }
            if (iy) { p = atomicAdd(&wctr[t.y], 1); adj[p] = s.y; }
            if (iz) { p = atomicAdd(&wctr[t.z], 1); adj[p] = s.z; }
            if (iw) { p = atomicAdd(&wctr[t.w], 1); adj[p] = s.w; }
        }
    }
}

// ---------------- softmax aggregation over CSR.
// one wave per node; 4 groups of 16 lanes; 16-deep edge pipeline (4 gathers in flight).
__global__ void __launch_bounds__(256) agg_kernel(const float* __restrict__ x,
                                                  const int* __restrict__ rowptr,
                                                  const int* __restrict__ adj,
                                                  float* __restrict__ outbuf) {
    const int lane = threadIdx.x & 63;
    const int grp = lane >> 4;      // 0..3: edge slot within quad
    const int sub = lane & 15;      // dims [4*sub, 4*sub+4)
    const int wid = (blockIdx.x * blockDim.x + threadIdx.x) >> 6;
    const int nwaves = (gridDim.x * blockDim.x) >> 6;
    for (int n = wid; n < NNODES; n += nwaves) {
        const int start = rowptr[n];
        const int deg = rowptr[n + 1] - start;
        float4 num = {0.f, 0.f, 0.f, 0.f}, den = {0.f, 0.f, 0.f, 0.f};
        for (int base = 0; base < deg; base += 16) {
            int eA = base + grp, eB = eA + 4, eC = eA + 8, eD = eA + 12;
            int sA = (eA < deg) ? adj[start + eA] : 0;
            int sB = (eB < deg) ? adj[start + eB] : 0;
            int sC = (eC < deg) ? adj[start + eC] : 0;
            int sD = (eD < deg) ? adj[start + eD] : 0;
            const float4 vA = *(const float4*)&x[(size_t)sA * DD + sub * 4];
            const float4 vB = *(const float4*)&x[(size_t)sB * DD + sub * 4];
            const float4 vC = *(const float4*)&x[(size_t)sC * DD + sub * 4];
            const float4 vD = *(const float4*)&x[(size_t)sD * DD + sub * 4];
            float valA = (eA < deg) ? 1.f : 0.f;
            float valB = (eB < deg) ? 1.f : 0.f;
            float valC = (eC < deg) ? 1.f : 0.f;
            float valD = (eD < deg) ? 1.f : 0.f;
#define ACC(v, val)                                                        \
            {                                                              \
                float m0 = fmaxf(v.x, 0.f) + 1e-7f; float x0 = __expf(m0) * val; \
                float m1 = fmaxf(v.y, 0.f) + 1e-7f; float x1 = __expf(m1) * val; \
                float m2 = fmaxf(v.z, 0.f) + 1e-7f; float x2 = __expf(m2) * val; \
                float m3 = fmaxf(v.w, 0.f) + 1e-7f; float x3 = __expf(m3) * val; \
                den.x += x0; num.x = fmaf(m0, x0, num.x);                  \
                den.y += x1; num.y = fmaf(m1, x1, num.y);                  \
                den.z += x2; num.z = fmaf(m2, x2, num.z);                  \
                den.w += x3; num.w = fmaf(m3, x3, num.w);                  \
            }
            ACC(vA, valA) ACC(vB, valB) ACC(vC, valC) ACC(vD, valD)
#undef ACC
        }
#pragma unroll
        for (int off = 16; off <= 32; off <<= 1) {
            num.x += __shfl_xor(num.x, off, 64);
            num.y += __shfl_xor(num.y, off, 64);
            num.z += __shfl_xor(num.z, off, 64);
            num.w += __shfl_xor(num.w, off, 64);
            den.x += __shfl_xor(den.x, off, 64);
            den.y += __shfl_xor(den.y, off, 64);
            den.z += __shfl_xor(den.z, off, 64);
            den.w += __shfl_xor(den.w, off, 64);
        }
        if (grp == 0) {
            const float4 xr = *(const float4*)&x[(size_t)n * DD + sub * 4];
            float4 o;
            o.x = num.x / (den.x + 1e-16f) + xr.x;
            o.y = num.y / (den.y + 1e-16f) + xr.y;
            o.z = num.z / (den.z + 1e-16f) + xr.z;
            o.w = num.w / (den.w + 1e-16f) + xr.w;
            *(float4*)&outbuf[(size_t)n * DD + sub * 4] = o;
        }
    }
}

// ---------------- node pass 1: h = out@W1 + b1 via transposed LDS tile;
// store h bf16-packed TRANSPOSED [pair][node] (coalesced); BN stats via LDS transpose.
__global__ void __launch_bounds__(256) node1_kernel(
        const float* __restrict__ outbuf,
        const float* __restrict__ W1,
        const float* __restrict__ b1,
        float* __restrict__ sums,
        float* __restrict__ sumsq,
        unsigned* __restrict__ hbufT) {
    __shared__ float smem[DD2 * (NT + 1)];
    __shared__ float sRed[2][DD2];
    float (*sOutT)[NT + 1] = (float (*)[NT + 1])smem;
    float (*sHT)[NT + 1] = (float (*)[NT + 1])smem;
    const int tid = threadIdx.x;
    const int n0 = blockIdx.x * NT;

#pragma unroll
    for (int j = 0; j < 16; ++j) {
        int f = j * 256 + tid;
        int n = f >> 6, d = f & 63;
        float o = (n0 + n < NNODES) ? outbuf[(size_t)n0 * DD + f] : 0.f;
        sOutT[d][n] = o;
    }
    __syncthreads();

    const int node = tid & 63;
    const int cg = __builtin_amdgcn_readfirstlane(tid >> 6);
    const int nn = n0 + node;
    const float* __restrict__ W1c = W1 + cg * 32;
    const float* __restrict__ b1c = b1 + cg * 32;
    float acc[32];
#pragma unroll
    for (int j = 0; j < 32; ++j) acc[j] = b1c[j];
#pragma unroll 16
    for (int k = 0; k < DD; ++k) {
        float a = sOutT[k][node];
#pragma unroll
        for (int j = 0; j < 32; ++j) acc[j] = fmaf(a, W1c[k * DD2 + j], acc[j]);
    }
    // store h transposed: pair p = cg*16+jp holds cols (2p, 2p+1); coalesced dwords
    if (nn < NNODES) {
#pragma unroll
        for (int jp = 0; jp < 16; ++jp)
            hbufT[(size_t)(cg * 16 + jp) * NNODES + nn] =
                bf16pack(acc[2 * jp], acc[2 * jp + 1]);
    }
    __syncthreads();

#pragma unroll
    for (int j = 0; j < 32; ++j) sHT[cg * 32 + j][node] = acc[j];
    __syncthreads();
    const int c = tid & 127, half = tid >> 7;
    float s = 0.f, q = 0.f;
#pragma unroll
    for (int i = 0; i < 32; ++i) {
        if (n0 + half * 32 + i < NNODES) {
            float v = sHT[c][half * 32 + i];
            s += v;
            q = fmaf(v, v, q);
        }
    }
    if (half) { sRed[0][c] = s; sRed[1][c] = q; }
    __syncthreads();
    if (!half) {
        atomicAdd(&sums[c], s + sRed[0][c]);
        atomicAdd(&sumsq[c], q + sRed[1][c]);
    }
}

// ---------------- BN finalize
__global__ void bn_finalize(const float* __restrict__ sums,
                            const float* __restrict__ sumsq,
                            const float* __restrict__ gamma,
                            const float* __restrict__ beta,
                            float* __restrict__ A, float* __restrict__ B) {
    int c = threadIdx.x;
    float inv_n = 1.0f / (float)NNODES;
    float mu = sums[c] * inv_n;
    float var = sumsq[c] * inv_n - mu * mu;
    float a = rsqrtf(var + 1e-5f) * gamma[c];
    A[c] = a;
    B[c] = beta[c] - mu * a;
}

// ---------------- node pass 2: h -> BN -> relu -> y=h@W2+b2 -> LN -> relu
__global__ void __launch_bounds__(256) node2_kernel(
        const unsigned* __restrict__ hbufT,
        const float* __restrict__ A,
        const float* __restrict__ B,
        const float* __restrict__ W2,
        const float* __restrict__ b2,
        const float* __restrict__ lng,
        const float* __restrict__ lnb,
        float* __restrict__ out) {
    __shared__ float sLN[2][4][NT];
    const int tid = threadIdx.x;
    const int n0 = blockIdx.x * NT;
    const int node = tid & 63;
    const int cg = __builtin_amdgcn_readfirstlane(tid >> 6);
    const int nn = n0 + node;
    const int nc = min(nn, NNODES - 1);
    const float* __restrict__ W2c = W2 + cg * 16;

    float y[16];
#pragma unroll
    for (int j = 0; j < 16; ++j) y[j] = b2[cg * 16 + j];

#pragma unroll 16
    for (int p = 0; p < 64; ++p) {       // pair p = cols (2p, 2p+1)
        unsigned u = hbufT[(size_t)p * NNODES + nc];   // coalesced across lanes
        float h0 = fmaxf(fmaf(bf16lo(u), A[2 * p], B[2 * p]), 0.f);
        float h1 = fmaxf(fmaf(bf16hi(u), A[2 * p + 1], B[2 * p + 1]), 0.f);
#pragma unroll
        for (int j = 0; j < 16; ++j) {
            y[j] = fmaf(h0, W2c[(2 * p) * DD + j], y[j]);
            y[j] = fmaf(h1, W2c[(2 * p + 1) * DD + j], y[j]);
        }
    }
    float ps = 0.f, pq = 0.f;
#pragma unroll
    for (int j = 0; j < 16; ++j) { ps += y[j]; pq = fmaf(y[j], y[j], pq); }
    sLN[0][cg][node] = ps;
    sLN[1][cg][node] = pq;
    __syncthreads();
    float s = sLN[0][0][node] + sLN[0][1][node] + sLN[0][2][node] + sLN[0][3][node];
    float q = sLN[1][0][node] + sLN[1][1][node] + sLN[1][2][node] + sLN[1][3][node];
    float mu = s * (1.0f / DD);
    float var = q * (1.0f / DD) - mu * mu;
    float rs = rsqrtf(var + 1e-5f);
    if (nn < NNODES) {
        float o[16];
#pragma unroll
        for (int j = 0; j < 16; ++j)
            o[j] = fmaxf(fmaf((y[j] - mu) * rs, lng[cg * 16 + j], lnb[cg * 16 + j]), 0.f);
        float4* op = (float4*)(out + (size_t)nn * DD + cg * 16);
#pragma unroll
        for (int i = 0; i < 4; ++i) op[i] = ((float4*)o)[i];
    }
}

extern "C" void kernel_launch(void* const* d_in, const int* in_sizes, int n_in,
                              void* d_out, int out_size, void* d_ws, size_t ws_size,
                              hipStream_t stream) {
    const float* x    = (const float*)d_in[0];
    const int*   ei   = (const int*)d_in[1];
    const float* W1   = (const float*)d_in[2];
    const float* b1   = (const float*)d_in[3];
    const float* bn_g = (const float*)d_in[4];
    const float* bn_b = (const float*)d_in[5];
    const float* W2   = (const float*)d_in[6];
    const float* b2   = (const float*)d_in[7];
    const float* ln_g = (const float*)d_in[8];
    const float* ln_b = (const float*)d_in[9];
    float* out = (float*)d_out;

    // ws: cnt[N] | sums[128] | sumsq[128] | A[128] | B[128] | bsum[512] | boff[512]
    //   | rowptr[N+1] | wctr[N] | adj[E] | hbufT[64*N] (uint)
    int*      cnt    = (int*)d_ws;
    float*    sums   = (float*)(cnt + NNODES);
    float*    sumsq  = sums + DD2;
    float*    A      = sumsq + DD2;
    float*    B      = A + DD2;
    int*      bsum   = (int*)(B + DD2);
    int*      boff   = bsum + 512;
    int*      rowptr = boff + 512;
    int*      wctr   = rowptr + NNODES + 1;
    int*      adj    = wctr + NNODES;
    unsigned* hbufT  = (unsigned*)(adj + NEDGES);

    // zero cnt + sums + sumsq (contiguous at start of ws)
    hipMemsetAsync(d_ws, 0, (size_t)(NNODES + 2 * DD2) * sizeof(int), stream);

    hist_kernel<<<RS_G * RS_NB, 256, 0, stream>>>(ei, cnt);
    scan1_kernel<<<SCAN_B, 256, 0, stream>>>(cnt, rowptr, bsum);
    scan2_kernel<<<1, 512, 0, stream>>>(bsum, boff);
    scan3_kernel<<<SCAN_B, 256, 0, stream>>>(rowptr, boff, wctr);
    scatter_kernel<<<RS_G * RS_NB, 256, 0, stream>>>(ei, wctr, adj);
    agg_kernel<<<2048, 256, 0, stream>>>(x, rowptr, adj, out);
    node1_kernel<<<NTILES, 256, 0, stream>>>(out, W1, b1, sums, sumsq, hbufT);
    bn_finalize<<<1, DD2, 0, stream>>>(sums, sumsq, bn_g, bn_b, A, B);
    node2_kernel<<<NTILES, 256, 0, stream>>>(hbufT, A, B, W2, b2, ln_g, ln_b, out);
}

// Round 10
// 223.556 us; speedup vs baseline: 1.3538x; 1.2807x over previous
//
#include <hip/hip_runtime.h>
#include <stdint.h>

#define NNODES 100000
#define NEDGES 1000000
#define DD 64
#define DD2 128
#define NT 64
#define NTILES ((NNODES + NT - 1) / NT)
#define SCAN_B ((NNODES + 256) / 256 + 1)
#define RS_G 8
#define RS_RANGE ((NNODES + RS_G - 1) / RS_G)
#define RS_NB 256

typedef __attribute__((ext_vector_type(8))) short s16x8;
typedef __attribute__((ext_vector_type(4))) float f32x4;

__device__ __forceinline__ unsigned bf16pack(float a, float b) {
    unsigned ua = __float_as_uint(a);
    unsigned ub = __float_as_uint(b);
    ua = (ua + 0x7fffu + ((ua >> 16) & 1u)) >> 16;
    ub = (ub + 0x7fffu + ((ub >> 16) & 1u)) >> 16;
    return ua | (ub << 16);
}
__device__ __forceinline__ unsigned short bf16of(float a) {
    unsigned ua = __float_as_uint(a);
    return (unsigned short)((ua + 0x7fffu + ((ua >> 16) & 1u)) >> 16);
}
__device__ __forceinline__ float bf16lo(unsigned u) { return __uint_as_float(u << 16); }
__device__ __forceinline__ float bf16hi(unsigned u) { return __uint_as_float(u & 0xffff0000u); }
__device__ __forceinline__ s16x8 as_s16x8(uint4 u) { union { uint4 a; s16x8 b; } c; c.a = u; return c.b; }

// ---------------- prep: W1T bf16 [128][64], W2T bf16 [64][128]
__global__ void prep_kernel(const float* __restrict__ W1, const float* __restrict__ W2,
                            unsigned short* __restrict__ W1T, unsigned short* __restrict__ W2T) {
    int i = blockIdx.x * 256 + threadIdx.x;
    if (i < DD * DD2) {                       // W1 [64][128]
        int k = i >> 7, c = i & 127;
        W1T[c * DD + k] = bf16of(W1[i]);
    } else if (i < 2 * DD * DD2) {            // W2 [128][64]
        int j = i - DD * DD2;
        int k = j >> 6, c = j & 63;
        W2T[c * DD2 + k] = bf16of(W2[j]);
    }
}

// ---------------- histogram (XCD-local ranges)
__global__ void hist_kernel(const int* __restrict__ ei, int* __restrict__ cnt) {
    const int group = blockIdx.x & (RS_G - 1);
    const int blk = blockIdx.x >> 3;
    const int lo = group * RS_RANGE;
    const int hi = min(lo + RS_RANGE, NNODES);
    for (int e4 = blk * 256 + threadIdx.x; e4 < NEDGES / 4; e4 += RS_NB * 256) {
        int4 t = *(const int4*)&ei[NEDGES + e4 * 4];
        if (t.x >= lo && t.x < hi) atomicAdd(&cnt[t.x], 1);
        if (t.y >= lo && t.y < hi) atomicAdd(&cnt[t.y], 1);
        if (t.z >= lo && t.z < hi) atomicAdd(&cnt[t.z], 1);
        if (t.w >= lo && t.w < hi) atomicAdd(&cnt[t.w], 1);
    }
}

__global__ void scan1_kernel(const int* __restrict__ cnt, int* __restrict__ rowptr,
                             int* __restrict__ bsum) {
    __shared__ int sc[256];
    const int t = threadIdx.x;
    const int i = blockIdx.x * 256 + t;
    int v = (i < NNODES) ? cnt[i] : 0;
    sc[t] = v;
    __syncthreads();
#pragma unroll
    for (int off = 1; off < 256; off <<= 1) {
        int tmp = (t >= off) ? sc[t - off] : 0;
        __syncthreads();
        sc[t] += tmp;
        __syncthreads();
    }
    if (i <= NNODES) rowptr[i] = sc[t] - v;
    if (t == 255) bsum[blockIdx.x] = sc[255];
}

__global__ void scan2_kernel(const int* __restrict__ bsum, int* __restrict__ boff) {
    __shared__ int sc[512];
    const int t = threadIdx.x;
    int v = (t < SCAN_B) ? bsum[t] : 0;
    sc[t] = v;
    __syncthreads();
#pragma unroll
    for (int off = 1; off < 512; off <<= 1) {
        int tmp = (t >= off) ? sc[t - off] : 0;
        __syncthreads();
        sc[t] += tmp;
        __syncthreads();
    }
    if (t < SCAN_B) boff[t] = sc[t] - v;
}

__global__ void scan3_kernel(int* __restrict__ rowptr, const int* __restrict__ boff,
                             int* __restrict__ wctr) {
    const int i = blockIdx.x * 256 + threadIdx.x;
    if (i <= NNODES) {
        int r = rowptr[i] + boff[blockIdx.x];
        rowptr[i] = r;
        if (i < NNODES) wctr[i] = r;
    }
}

__global__ void scatter_kernel(const int* __restrict__ ei, int* __restrict__ wctr,
                               int* __restrict__ adj) {
    const int group = blockIdx.x & (RS_G - 1);
    const int blk = blockIdx.x >> 3;
    const int lo = group * RS_RANGE;
    const int hi = min(lo + RS_RANGE, NNODES);
    for (int e4 = blk * 256 + threadIdx.x; e4 < NEDGES / 4; e4 += RS_NB * 256) {
        int4 t = *(const int4*)&ei[NEDGES + e4 * 4];
        bool ix = (t.x >= lo && t.x < hi);
        bool iy = (t.y >= lo && t.y < hi);
        bool iz = (t.z >= lo && t.z < hi);
        bool iw = (t.w >= lo && t.w < hi);
        if (ix | iy | iz | iw) {
            int4 s = *(const int4*)&ei[e4 * 4];
            int p;
            if (ix) { p = atomicAdd(&wctr[t.x], 1); adj[p] = s.x; }
            if (iy) { p = atomicAdd(&wctr[t.y], 1); adj[p] = s.y; }
            if (iz) { p = atomicAdd(&wctr[t.z], 1); adj[p] = s.z; }
            if (iw) { p = atomicAdd(&wctr[t.w], 1); adj[p] = s.w; }
        }
    }
}

// ---------------- softmax aggregation over CSR; writes bf16 out-tile
__global__ void __launch_bounds__(256) agg_kernel(const float* __restrict__ x,
                                                  const int* __restrict__ rowptr,
                                                  const int* __restrict__ adj,
                                                  unsigned* __restrict__ xbf_u) {
    const int lane = threadIdx.x & 63;
    const int grp = lane >> 4;
    const int sub = lane & 15;
    const int wid = (blockIdx.x * blockDim.x + threadIdx.x) >> 6;
    const int nwaves = (gridDim.x * blockDim.x) >> 6;
    for (int n = wid; n < NNODES; n += nwaves) {
        const int start = rowptr[n];
        const int deg = rowptr[n + 1] - start;
        float4 num = {0.f, 0.f, 0.f, 0.f}, den = {0.f, 0.f, 0.f, 0.f};
        for (int base = 0; base < deg; base += 16) {
            int eA = base + grp, eB = eA + 4, eC = eA + 8, eD = eA + 12;
            int sA = (eA < deg) ? adj[start + eA] : 0;
            int sB = (eB < deg) ? adj[start + eB] : 0;
            int sC = (eC < deg) ? adj[start + eC] : 0;
            int sD = (eD < deg) ? adj[start + eD] : 0;
            const float4 vA = *(const float4*)&x[(size_t)sA * DD + sub * 4];
            const float4 vB = *(const float4*)&x[(size_t)sB * DD + sub * 4];
            const float4 vC = *(const float4*)&x[(size_t)sC * DD + sub * 4];
            const float4 vD = *(const float4*)&x[(size_t)sD * DD + sub * 4];
            float valA = (eA < deg) ? 1.f : 0.f;
            float valB = (eB < deg) ? 1.f : 0.f;
            float valC = (eC < deg) ? 1.f : 0.f;
            float valD = (eD < deg) ? 1.f : 0.f;
#define ACC(v, val)                                                        \
            {                                                              \
                float m0 = fmaxf(v.x, 0.f) + 1e-7f; float x0 = __expf(m0) * val; \
                float m1 = fmaxf(v.y, 0.f) + 1e-7f; float x1 = __expf(m1) * val; \
                float m2 = fmaxf(v.z, 0.f) + 1e-7f; float x2 = __expf(m2) * val; \
                float m3 = fmaxf(v.w, 0.f) + 1e-7f; float x3 = __expf(m3) * val; \
                den.x += x0; num.x = fmaf(m0, x0, num.x);                  \
                den.y += x1; num.y = fmaf(m1, x1, num.y);                  \
                den.z += x2; num.z = fmaf(m2, x2, num.z);                  \
                den.w += x3; num.w = fmaf(m3, x3, num.w);                  \
            }
            ACC(vA, valA) ACC(vB, valB) ACC(vC, valC) ACC(vD, valD)
#undef ACC
        }
#pragma unroll
        for (int off = 16; off <= 32; off <<= 1) {
            num.x += __shfl_xor(num.x, off, 64);
            num.y += __shfl_xor(num.y, off, 64);
            num.z += __shfl_xor(num.z, off, 64);
            num.w += __shfl_xor(num.w, off, 64);
            den.x += __shfl_xor(den.x, off, 64);
            den.y += __shfl_xor(den.y, off, 64);
            den.z += __shfl_xor(den.z, off, 64);
            den.w += __shfl_xor(den.w, off, 64);
        }
        if (grp == 0) {
            const float4 xr = *(const float4*)&x[(size_t)n * DD + sub * 4];
            float o0 = num.x / (den.x + 1e-16f) + xr.x;
            float o1 = num.y / (den.y + 1e-16f) + xr.y;
            float o2 = num.z / (den.z + 1e-16f) + xr.z;
            float o3 = num.w / (den.w + 1e-16f) + xr.w;
            uint2 pk = {bf16pack(o0, o1), bf16pack(o2, o3)};
            *(uint2*)&xbf_u[(size_t)n * 32 + sub * 2] = pk;
        }
    }
}

// ---------------- node1: h = out@W1 + b1 via MFMA; BN stats; coalesced bf16 h store
__global__ void __launch_bounds__(256) node1_mfma(
        const unsigned short* __restrict__ xbf,   // [N][64] bf16
        const unsigned* __restrict__ W1Tg,        // [128][64] bf16 as uints (4096)
        const float* __restrict__ b1,
        float* __restrict__ sums, float* __restrict__ sumsq,
        unsigned* __restrict__ hbuf_u) {          // [N][128] bf16 as uints
    __shared__ unsigned sW[4096];                 // swizzled W1T (16KB)
    __shared__ unsigned short sH[NT * DD2];       // h tile bf16 (16KB)
    __shared__ float sRed[2][DD2];
    const int tid = threadIdx.x;
    // stage W1T with 16B-slot swizzle: byte = c*128 + (w ^ ((c&7)<<4))
    for (int i = tid; i < 4096; i += 256) {
        unsigned v = W1Tg[i];
        int byte = i << 2;
        int c = byte >> 7;
        int w = byte & 127;
        sW[(c << 5) + ((w ^ ((c & 7) << 4)) >> 2)] = v;
    }
    if (tid < DD2) { sRed[0][tid] = 0.f; sRed[1][tid] = 0.f; }
    __syncthreads();

    const int n0 = blockIdx.x * NT;
    const int lane = tid & 63;
    const int wv = tid >> 6;
    const int r = lane & 15;
    const int kb = lane >> 4;

    // A-frags: rows n0+wv*16+r, k = ks*32 + kb*8 + i
    int arow = n0 + wv * 16 + r;
    if (arow >= NNODES) arow = NNODES - 1;
    const char* xb = (const char*)xbf;
    s16x8 af0 = as_s16x8(*(const uint4*)(xb + (size_t)arow * 128 + kb * 16));
    s16x8 af1 = as_s16x8(*(const uint4*)(xb + (size_t)arow * 128 + 64 + kb * 16));

    f32x4 acc[8];
#pragma unroll
    for (int ct = 0; ct < 8; ++ct) {
        acc[ct] = (f32x4){0.f, 0.f, 0.f, 0.f};
        int c = ct * 16 + r;
        const char* wp = (const char*)sW + c * 128;
        s16x8 bf0 = *(const s16x8*)(wp + ((kb * 16) ^ ((c & 7) << 4)));
        acc[ct] = __builtin_amdgcn_mfma_f32_16x16x32_bf16(af0, bf0, acc[ct], 0, 0, 0);
        s16x8 bf1 = *(const s16x8*)(wp + ((64 + kb * 16) ^ ((c & 7) << 4)));
        acc[ct] = __builtin_amdgcn_mfma_f32_16x16x32_bf16(af1, bf1, acc[ct], 0, 0, 0);
    }

    // bias + stats (D layout: row = kb*4+rg, col = ct*16+r) + bf16 into sH
    bool valid[4];
#pragma unroll
    for (int rg = 0; rg < 4; ++rg) valid[rg] = (n0 + wv * 16 + kb * 4 + rg) < NNODES;
#pragma unroll
    for (int ct = 0; ct < 8; ++ct) {
        int c = ct * 16 + r;
        float bb = b1[c];
        float s = 0.f, q = 0.f;
#pragma unroll
        for (int rg = 0; rg < 4; ++rg) {
            float v = acc[ct][rg] + bb;
            acc[ct][rg] = v;
            sH[(wv * 16 + kb * 4 + rg) * DD2 + c] = bf16of(v);
            if (valid[rg]) { s += v; q = fmaf(v, v, q); }
        }
        s += __shfl_xor(s, 16, 64); s += __shfl_xor(s, 32, 64);
        q += __shfl_xor(q, 16, 64); q += __shfl_xor(q, 32, 64);
        if (kb == 0) {
            atomicAdd(&sRed[0][c], s);
            atomicAdd(&sRed[1][c], q);
        }
    }
    __syncthreads();
    if (tid < DD2) {
        atomicAdd(&sums[tid], sRed[0][tid]);
        atomicAdd(&sumsq[tid], sRed[1][tid]);
    }
    // coalesced h store (uint4 rows)
    const uint4* sH4 = (const uint4*)sH;
    uint4* dst = (uint4*)hbuf_u + (size_t)n0 * 16;
#pragma unroll
    for (int j = 0; j < 4; ++j) dst[j * 256 + tid] = sH4[j * 256 + tid];
}

// ---------------- BN finalize
__global__ void bn_finalize(const float* __restrict__ sums, const float* __restrict__ sumsq,
                            const float* __restrict__ gamma, const float* __restrict__ beta,
                            float* __restrict__ A, float* __restrict__ B) {
    int c = threadIdx.x;
    float inv_n = 1.0f / (float)NNODES;
    float mu = sums[c] * inv_n;
    float var = sumsq[c] * inv_n - mu * mu;
    float a = rsqrtf(var + 1e-5f) * gamma[c];
    A[c] = a;
    B[c] = beta[c] - mu * a;
}

// ---------------- node2: h -> BN -> relu -> y = h@W2 + b2 (MFMA) -> LN -> relu
__global__ void __launch_bounds__(256) node2_mfma(
        const unsigned short* __restrict__ hbuf,  // [N][128] bf16
        const float* __restrict__ A, const float* __restrict__ B,
        const unsigned* __restrict__ W2Tg,        // [64][128] bf16 as uints (4096)
        const float* __restrict__ b2,
        const float* __restrict__ lng, const float* __restrict__ lnb,
        float* __restrict__ out) {
    __shared__ unsigned sW[4096];                 // swizzled W2T (16KB)
    const int tid = threadIdx.x;
    for (int i = tid; i < 4096; i += 256) {
        unsigned v = W2Tg[i];
        int byte = i << 2;
        int c = byte >> 8;
        int w = byte & 255;
        sW[(c << 6) + ((w ^ ((c & 15) << 4)) >> 2)] = v;
    }
    __syncthreads();

    const int n0 = blockIdx.x * NT;
    const int lane = tid & 63;
    const int wv = tid >> 6;
    const int r = lane & 15;
    const int kb = lane >> 4;

    int arow = n0 + wv * 16 + r;
    if (arow >= NNODES) arow = NNODES - 1;
    const char* hb = (const char*)hbuf;

    s16x8 hfrag[4];
#pragma unroll
    for (int ks = 0; ks < 4; ++ks) {
        uint4 u = *(const uint4*)(hb + (size_t)arow * 256 + ks * 64 + kb * 16);
        int kbase = ks * 32 + kb * 8;
        float4 a0 = *(const float4*)&A[kbase];
        float4 a1 = *(const float4*)&A[kbase + 4];
        float4 c0 = *(const float4*)&B[kbase];
        float4 c1 = *(const float4*)&B[kbase + 4];
        float f0 = fmaxf(fmaf(bf16lo(u.x), a0.x, c0.x), 0.f);
        float f1 = fmaxf(fmaf(bf16hi(u.x), a0.y, c0.y), 0.f);
        float f2 = fmaxf(fmaf(bf16lo(u.y), a0.z, c0.z), 0.f);
        float f3 = fmaxf(fmaf(bf16hi(u.y), a0.w, c0.w), 0.f);
        float f4 = fmaxf(fmaf(bf16lo(u.z), a1.x, c1.x), 0.f);
        float f5 = fmaxf(fmaf(bf16hi(u.z), a1.y, c1.y), 0.f);
        float f6 = fmaxf(fmaf(bf16lo(u.w), a1.z, c1.z), 0.f);
        float f7 = fmaxf(fmaf(bf16hi(u.w), a1.w, c1.w), 0.f);
        uint4 pk = {bf16pack(f0, f1), bf16pack(f2, f3), bf16pack(f4, f5), bf16pack(f6, f7)};
        hfrag[ks] = as_s16x8(pk);
    }

    f32x4 y[4];
#pragma unroll
    for (int ct = 0; ct < 4; ++ct) {
        y[ct] = (f32x4){0.f, 0.f, 0.f, 0.f};
        int c = ct * 16 + r;
        const char* wp = (const char*)sW + c * 256;
#pragma unroll
        for (int ks = 0; ks < 4; ++ks) {
            s16x8 bfrag = *(const s16x8*)(wp + ((ks * 64 + kb * 16) ^ ((c & 15) << 4)));
            y[ct] = __builtin_amdgcn_mfma_f32_16x16x32_bf16(hfrag[ks], bfrag, y[ct], 0, 0, 0);
        }
        float bb = b2[c];
#pragma unroll
        for (int rg = 0; rg < 4; ++rg) y[ct][rg] += bb;
    }

    // LayerNorm per node (row = kb*4+rg); reduce over r via xor 1,2,4,8
    float mu[4], rs[4];
#pragma unroll
    for (int rg = 0; rg < 4; ++rg) {
        float sv = 0.f, qv = 0.f;
#pragma unroll
        for (int ct = 0; ct < 4; ++ct) { float v = y[ct][rg]; sv += v; qv = fmaf(v, v, qv); }
#pragma unroll
        for (int off = 1; off < 16; off <<= 1) {
            sv += __shfl_xor(sv, off, 64);
            qv += __shfl_xor(qv, off, 64);
        }
        float m = sv * (1.0f / DD);
        float var = qv * (1.0f / DD) - m * m;
        mu[rg] = m;
        rs[rg] = rsqrtf(var + 1e-5f);
    }
#pragma unroll
    for (int ct = 0; ct < 4; ++ct) {
        int c = ct * 16 + r;
        float g = lng[c], bb = lnb[c];
#pragma unroll
        for (int rg = 0; rg < 4; ++rg) {
            int node = n0 + wv * 16 + kb * 4 + rg;
            if (node < NNODES)
                out[(size_t)node * DD + c] = fmaxf(fmaf((y[ct][rg] - mu[rg]) * rs[rg], g, bb), 0.f);
        }
    }
}

extern "C" void kernel_launch(void* const* d_in, const int* in_sizes, int n_in,
                              void* d_out, int out_size, void* d_ws, size_t ws_size,
                              hipStream_t stream) {
    const float* x    = (const float*)d_in[0];
    const int*   ei   = (const int*)d_in[1];
    const float* W1   = (const float*)d_in[2];
    const float* b1   = (const float*)d_in[3];
    const float* bn_g = (const float*)d_in[4];
    const float* bn_b = (const float*)d_in[5];
    const float* W2   = (const float*)d_in[6];
    const float* b2   = (const float*)d_in[7];
    const float* ln_g = (const float*)d_in[8];
    const float* ln_b = (const float*)d_in[9];
    float* out = (float*)d_out;

    char* p = (char*)d_ws;
    auto alloc = [&](size_t bytes) {
        p = (char*)(((uintptr_t)p + 15) & ~(uintptr_t)15);
        char* r = p; p += bytes; return (void*)r;
    };
    int*   cnt    = (int*)alloc(NNODES * 4);
    float* sums   = (float*)alloc(DD2 * 4);
    float* sumsq  = (float*)alloc(DD2 * 4);
    float* A      = (float*)alloc(DD2 * 4);
    float* B      = (float*)alloc(DD2 * 4);
    int*   bsum   = (int*)alloc(512 * 4);
    int*   boff   = (int*)alloc(512 * 4);
    int*   rowptr = (int*)alloc((NNODES + 1) * 4);
    int*   wctr   = (int*)alloc(NNODES * 4);
    int*   adj    = (int*)alloc(NEDGES * 4);
    unsigned short* W1T = (unsigned short*)alloc(DD * DD2 * 2);
    unsigned short* W2T = (unsigned short*)alloc(DD * DD2 * 2);
    unsigned short* xbf = (unsigned short*)alloc((size_t)NNODES * DD * 2);
    unsigned short* hbuf = (unsigned short*)alloc((size_t)NNODES * DD2 * 2);

    // zero cnt + sums + sumsq (contiguous)
    hipMemsetAsync(cnt, 0, (size_t)NNODES * 4 + 2 * DD2 * 4, stream);

    prep_kernel<<<(2 * DD * DD2 + 255) / 256, 256, 0, stream>>>(W1, W2, W1T, W2T);
    hist_kernel<<<RS_G * RS_NB, 256, 0, stream>>>(ei, cnt);
    scan1_kernel<<<SCAN_B, 256, 0, stream>>>(cnt, rowptr, bsum);
    scan2_kernel<<<1, 512, 0, stream>>>(bsum, boff);
    scan3_kernel<<<SCAN_B, 256, 0, stream>>>(rowptr, boff, wctr);
    scatter_kernel<<<RS_G * RS_NB, 256, 0, stream>>>(ei, wctr, adj);
    agg_kernel<<<2048, 256, 0, stream>>>(x, rowptr, adj, (unsigned*)xbf);
    node1_mfma<<<NTILES, 256, 0, stream>>>(xbf, (const unsigned*)W1T, b1, sums, sumsq,
                                           (unsigned*)hbuf);
    bn_finalize<<<1, DD2, 0, stream>>>(sums, sumsq, bn_g, bn_b, A, B);
    node2_mfma<<<NTILES, 256, 0, stream>>>(hbuf, A, B, (const unsigned*)W2T, b2,
                                           ln_g, ln_b, out);
}